// Round 2
// baseline (299.717 us; speedup 1.0000x reference)
//
#include <hip/hip_runtime.h>
#include <hip/hip_cooperative_groups.h>

namespace cg = cooperative_groups;

#define BB 4
#define CIN 256      // CK == CQ == CV
#define CO 64
#define NN 576       // 24*24
#define NKC 18       // 576/32 k-chunks
#define NQT 36       // q-subtiles of 16

typedef __attribute__((ext_vector_type(8))) short short8;
typedef __attribute__((ext_vector_type(4))) float floatx4;

__device__ __forceinline__ unsigned short f2bf(float f) {
    unsigned int u = __float_as_uint(f);
    unsigned int r = (u + 0x7fffu + ((u >> 16) & 1u)) >> 16;   // RNE
    return (unsigned short)r;
}

// ------------------------------------------------------------------
// Stage 1a: fused x-load + W-pack + proj GEMM + exp:
//   e[b,n,o] = exp(2*(sum_c x[b,c,n]*W[o,c] + bias[o]))
// tile = 256c x 16n f32 in LDS (pad 17), A-frag from LDS, B-frag from
// global W (L2-hot). One block per (z,b,nt16).
__device__ __forceinline__ void stage_proj(
    int z, int b, int nt16, int t,
    const float* __restrict__ key, const float* __restrict__ query,
    const float* __restrict__ Wk, const float* __restrict__ Wq,
    const float* __restrict__ bk, const float* __restrict__ bq,
    float* __restrict__ ek, float* __restrict__ eq,
    float* tile /* >= 256*17 floats */)
{
    int l = t & 63, w = t >> 6;
    const float* src  = z ? query : key;
    const float* W    = z ? Wq : Wk;
    const float* bias = z ? bq : bk;
    float*       outp = z ? eq : ek;

    const float* sbase = src + (size_t)b * CIN * NN + (size_t)nt16 * 16;
    #pragma unroll
    for (int i = 0; i < 4; ++i) {
        int f4  = t + i * 256;          // 0..1023
        int c   = f4 >> 2;
        int col = (f4 & 3) * 4;
        float4 v = *(const float4*)(sbase + (size_t)c * NN + col);
        float* d = &tile[c * 17 + col];
        d[0] = v.x; d[1] = v.y; d[2] = v.z; d[3] = v.w;
    }
    __syncthreads();

    int m = l & 15;                      // n row within tile
    int o = w * 16 + (l & 15);           // o column (wave w -> o-subtile w)
    floatx4 acc = {0.f, 0.f, 0.f, 0.f};
    #pragma unroll
    for (int kc = 0; kc < 8; ++kc) {
        int cb = kc * 32 + (l >> 4) * 8;
        short8 a;
        #pragma unroll
        for (int j = 0; j < 8; ++j)
            a[j] = (short)f2bf(tile[(cb + j) * 17 + m]);
        const float4* p = (const float4*)(W + (size_t)o * CIN + cb);
        float4 v0 = p[0], v1 = p[1];
        short8 bfr;
        bfr[0] = (short)f2bf(v0.x); bfr[1] = (short)f2bf(v0.y);
        bfr[2] = (short)f2bf(v0.z); bfr[3] = (short)f2bf(v0.w);
        bfr[4] = (short)f2bf(v1.x); bfr[5] = (short)f2bf(v1.y);
        bfr[6] = (short)f2bf(v1.z); bfr[7] = (short)f2bf(v1.w);
        acc = __builtin_amdgcn_mfma_f32_16x16x32_bf16(a, bfr, acc, 0, 0, 0);
    }

    int n0 = nt16 * 16;
    float bv = bias[o];
    #pragma unroll
    for (int rr = 0; rr < 4; ++rr) {
        int row = (l >> 4) * 4 + rr;
        outp[((size_t)b * NN + n0 + row) * CO + o] = __expf(2.0f * (acc[rr] + bv));
    }
}

// ------------------------------------------------------------------
// Stage 1b: value -> bf16 A-fragments (round-0 verified layout).
// A-frag elem j of lane l = V[ct*16 + (l&15)][kc*32 + (l>>4)*8 + j]
__device__ __forceinline__ void stage_vpack(
    int funit, int l, const float* __restrict__ value,
    unsigned short* __restrict__ Vp)
{
    int b  = funit / 288;
    int r  = funit % 288;
    int ct = r / 18;
    int kc = r % 18;
    int c = ct * 16 + (l & 15);
    int k = kc * 32 + (l >> 4) * 8;
    const float4* p = (const float4*)(value + ((size_t)b * CIN + c) * NN + k);
    float4 v0 = p[0], v1 = p[1];
    uint4 u;
    u.x = (unsigned)f2bf(v0.x) | ((unsigned)f2bf(v0.y) << 16);
    u.y = (unsigned)f2bf(v0.z) | ((unsigned)f2bf(v0.w) << 16);
    u.z = (unsigned)f2bf(v1.x) | ((unsigned)f2bf(v1.y) << 16);
    u.w = (unsigned)f2bf(v1.z) | ((unsigned)f2bf(v1.w) << 16);
    *(uint4*)(Vp + (((size_t)b * 16 + ct) * NKC + kc) * 512 + l * 8) = u;
}

// ------------------------------------------------------------------
// Stage 2: attn scores + sigmoid + bf16 B-fragment pack (verified body).
// score(k,q) = C - sum_o 2*wf[o]/(1 + ek[k,o]*eq[q,o]),  C = sum wf + bf.
__device__ __forceinline__ void stage_attn(
    int b, int ky, int qx, int t,
    const float* __restrict__ ek, const float* __restrict__ eq,
    const float* __restrict__ wf, const float* __restrict__ bfp,
    unsigned short* __restrict__ Bp,
    float* eqs /* 64*65 */, float* sc /* 32*65 */)
{
    int k0 = ky * 32;
    int q0 = qx * 64;
    int l  = t & 63;
    int w  = __builtin_amdgcn_readfirstlane(t >> 6);

    // coalesced global -> LDS (16 KB contiguous span)
    const float4* esrc = (const float4*)(eq + ((size_t)b * NN + q0) * CO);
    #pragma unroll
    for (int i = 0; i < 4; ++i) {
        int f4  = t + i * 256;                 // 0..1023
        int row = f4 >> 4, c4 = (f4 & 15) * 4;
        float4 v = esrc[f4];
        int a = row * 65 + c4;
        eqs[a + 0] = v.x; eqs[a + 1] = v.y; eqs[a + 2] = v.z; eqs[a + 3] = v.w;
    }

    float4 w2v[16];
    float C = bfp[0];
    const float4* wfp4 = (const float4*)wf;
    #pragma unroll
    for (int i = 0; i < 16; ++i) {
        float4 wv = wfp4[i];
        C += wv.x + wv.y + wv.z + wv.w;
        wv.x *= 2.0f; wv.y *= 2.0f; wv.z *= 2.0f; wv.w *= 2.0f;
        w2v[i] = wv;
    }
    __syncthreads();

    // lane l's q-row into VGPRs (2-way bank aliasing only = free)
    float4 eqv[16];
    #pragma unroll
    for (int i = 0; i < 16; ++i) {
        int a = l * 65 + i * 4;
        eqv[i].x = eqs[a]; eqv[i].y = eqs[a + 1];
        eqv[i].z = eqs[a + 2]; eqv[i].w = eqs[a + 3];
    }

    #pragma unroll 1
    for (int kk = 0; kk < 8; ++kk) {
        int k = k0 + w * 8 + kk;               // wave-uniform
        const float4* ekr = (const float4*)(ek + ((size_t)b * NN + k) * CO);
        float a0 = 0.f, a1 = 0.f, a2 = 0.f, a3 = 0.f;
        #pragma unroll
        for (int i = 0; i < 16; ++i) {
            float4 k4 = ekr[i];
            float4 e4 = eqv[i];
            float4 w4 = w2v[i];
            a0 = fmaf(w4.x, __builtin_amdgcn_rcpf(fmaf(k4.x, e4.x, 1.0f)), a0);
            a1 = fmaf(w4.y, __builtin_amdgcn_rcpf(fmaf(k4.y, e4.y, 1.0f)), a1);
            a2 = fmaf(w4.z, __builtin_amdgcn_rcpf(fmaf(k4.z, e4.z, 1.0f)), a2);
            a3 = fmaf(w4.w, __builtin_amdgcn_rcpf(fmaf(k4.w, e4.w, 1.0f)), a3);
        }
        float score = C - (a0 + a1) - (a2 + a3);
        float sg = __builtin_amdgcn_rcpf(1.0f + __expf(-score));
        sc[(w * 8 + kk) * 65 + l] = sg;
    }
    __syncthreads();

    // pack: wave w -> q-subtile w; fragment elem j = sc[(l>>4)*8+j][w*16+(l&15)]
    int col = w * 16 + (l & 15);
    int row = (l >> 4) * 8;
    uint4 o;
    o.x = (unsigned)f2bf(sc[(row + 0) * 65 + col]) | ((unsigned)f2bf(sc[(row + 1) * 65 + col]) << 16);
    o.y = (unsigned)f2bf(sc[(row + 2) * 65 + col]) | ((unsigned)f2bf(sc[(row + 3) * 65 + col]) << 16);
    o.z = (unsigned)f2bf(sc[(row + 4) * 65 + col]) | ((unsigned)f2bf(sc[(row + 5) * 65 + col]) << 16);
    o.w = (unsigned)f2bf(sc[(row + 6) * 65 + col]) | ((unsigned)f2bf(sc[(row + 7) * 65 + col]) << 16);
    size_t qt = (size_t)qx * 4 + w;
    *(uint4*)(Bp + (((size_t)b * NQT + qt) * NKC + ky) * 512 + l * 8) = o;
}

// ------------------------------------------------------------------
// Stage 3: out[b,c,q] = sum_k V[b,c,k]*attn[b,k,q] via MFMA (round-0
// verified body: Vp frags + k-split + LDS reduce).
__device__ __forceinline__ void stage_av(
    int b, int ct, int qx, int t,
    const unsigned short* __restrict__ Vp,
    const unsigned short* __restrict__ Bp,
    float* __restrict__ out, float* red /* 4*64*17 floats */)
{
    int l = t & 63;
    int w = __builtin_amdgcn_readfirstlane(t >> 6);

    floatx4 acc[4] = {{0.f,0.f,0.f,0.f},{0.f,0.f,0.f,0.f},
                      {0.f,0.f,0.f,0.f},{0.f,0.f,0.f,0.f}};

    const unsigned short* abase = Vp + ((size_t)b * 16 + ct) * NKC * 512 + l * 8;
    const unsigned short* bbase = Bp + ((size_t)b * NQT + (size_t)qx * 4) * NKC * 512 + l * 8;

    for (int kc = w; kc < NKC; kc += 4) {
        short8 a = *(const short8*)(abase + (size_t)kc * 512);
        #pragma unroll
        for (int qt = 0; qt < 4; ++qt) {
            short8 bq = *(const short8*)(bbase + ((size_t)qt * NKC + kc) * 512);
            acc[qt] = __builtin_amdgcn_mfma_f32_16x16x32_bf16(a, bq, acc[qt], 0, 0, 0);
        }
    }

    #pragma unroll
    for (int qt = 0; qt < 4; ++qt)
        #pragma unroll
        for (int r = 0; r < 4; ++r)
            red[(w * 64 + l) * 17 + qt * 4 + r] = acc[qt][r];
    __syncthreads();

    int q = qx * 64 + w * 16 + (l & 15);
    #pragma unroll
    for (int r = 0; r < 4; ++r) {
        float s = red[(0 * 64 + l) * 17 + w * 4 + r] + red[(1 * 64 + l) * 17 + w * 4 + r]
                + red[(2 * 64 + l) * 17 + w * 4 + r] + red[(3 * 64 + l) * 17 + w * 4 + r];
        int c = ct * 16 + (l >> 4) * 4 + r;
        out[((size_t)b * CIN + c) * NN + q] = s;
    }
}

// ------------------------------------------------------------------
// Single cooperative kernel: stage1 (proj 288 blocks || vpack 288 blocks)
// -> grid.sync -> stage2 attn (all 648) -> grid.sync -> stage3 av (576).
// LDS 25 KB, 3 blocks/CU => 768-block co-residency >= 648.
__global__ void __launch_bounds__(256, 3) mega_fused(
    const float* __restrict__ key, const float* __restrict__ query,
    const float* __restrict__ value,
    const float* __restrict__ Wk, const float* __restrict__ bk,
    const float* __restrict__ Wq, const float* __restrict__ bq,
    const float* __restrict__ wf, const float* __restrict__ bfp,
    float* __restrict__ ek, float* __restrict__ eq,
    unsigned short* __restrict__ Vp, unsigned short* __restrict__ Bp,
    float* __restrict__ out)
{
    __shared__ float smem[64 * 65 + 32 * 65];   // 25 KB, reused per stage
    cg::grid_group grid = cg::this_grid();
    int bid = blockIdx.x;
    int t = threadIdx.x, l = t & 63, w = t >> 6;

    if (bid < 288) {
        int z = bid / 144, r = bid % 144;
        int b = r / 36, nt16 = r % 36;
        stage_proj(z, b, nt16, t, key, query, Wk, Wq, bk, bq, ek, eq, smem);
    } else if (bid < 576) {
        stage_vpack((bid - 288) * 4 + w, l, value, Vp);
    }
    grid.sync();

    {
        int b = bid / 162, r = bid % 162;
        int ky = r / 9, qx = r % 9;
        stage_attn(b, ky, qx, t, ek, eq, wf, bfp, Bp, smem, smem + 64 * 65);
    }
    grid.sync();

    if (bid < 576) {
        int b = bid / 144, r = bid % 144;
        int ct = r / 9, qx = r % 9;
        stage_av(b, ct, qx, t, Vp, Bp, out, smem);
    }
}

// ------------------------------------------------------------------
// Fallback wrappers (non-cooperative 4-kernel path; same device bodies)
__global__ void __launch_bounds__(256) proj_kernel(
    const float* __restrict__ key, const float* __restrict__ query,
    const float* __restrict__ Wk, const float* __restrict__ Wq,
    const float* __restrict__ bk, const float* __restrict__ bq,
    float* __restrict__ ek, float* __restrict__ eq)
{
    __shared__ float tile[256 * 17];
    stage_proj(blockIdx.z, blockIdx.y, blockIdx.x, threadIdx.x,
               key, query, Wk, Wq, bk, bq, ek, eq, tile);
}

__global__ void __launch_bounds__(256) vpack_kernel(
    const float* __restrict__ value, unsigned short* __restrict__ Vp)
{
    stage_vpack(blockIdx.x * 4 + (threadIdx.x >> 6), threadIdx.x & 63, value, Vp);
}

__global__ void __launch_bounds__(256, 3) attn_kernel(
    const float* __restrict__ ek, const float* __restrict__ eq,
    const float* __restrict__ wf, const float* __restrict__ bfp,
    unsigned short* __restrict__ Bp)
{
    __shared__ float smem[64 * 65 + 32 * 65];
    stage_attn(blockIdx.z, blockIdx.y, blockIdx.x, threadIdx.x,
               ek, eq, wf, bfp, Bp, smem, smem + 64 * 65);
}

__global__ void __launch_bounds__(256) av_kernel(
    const unsigned short* __restrict__ Vp,
    const unsigned short* __restrict__ Bp, float* __restrict__ out)
{
    __shared__ float red[4 * 64 * 17];
    stage_av(blockIdx.z, blockIdx.y, blockIdx.x, threadIdx.x, Vp, Bp, out, red);
}

// ------------------------------------------------------------------
extern "C" void kernel_launch(void* const* d_in, const int* in_sizes, int n_in,
                              void* d_out, int out_size, void* d_ws, size_t ws_size,
                              hipStream_t stream) {
    const float* key   = (const float*)d_in[0];
    const float* query = (const float*)d_in[1];
    const float* value = (const float*)d_in[2];
    const float* Wk    = (const float*)d_in[3];
    const float* bk    = (const float*)d_in[4];
    const float* Wq    = (const float*)d_in[5];
    const float* bq    = (const float*)d_in[6];
    const float* wf    = (const float*)d_in[7];
    const float* bf    = (const float*)d_in[8];
    float* out = (float*)d_out;

    float* ws = (float*)d_ws;
    float* ek = ws;                                        // BB*NN*CO f32
    float* eq = ek + (size_t)BB * NN * CO;
    unsigned short* Bp = (unsigned short*)(eq + (size_t)BB * NN * CO);
    unsigned short* Vp = Bp + (size_t)BB * NQT * NKC * 512;   // Bp: 1,327,104 us
    // Vp: 589,824 us; total ws ~ 6 MB

    void* args[] = {
        (void*)&key, (void*)&query, (void*)&value,
        (void*)&Wk, (void*)&bk, (void*)&Wq, (void*)&bq,
        (void*)&wf, (void*)&bf,
        (void*)&ek, (void*)&eq, (void*)&Vp, (void*)&Bp, (void*)&out
    };
    hipError_t err = hipLaunchCooperativeKernel(
        (const void*)mega_fused, dim3(648), dim3(256), args, 0, stream);

    if (err != hipSuccess) {
        // non-cooperative fallback: 4 small kernels
        dim3 gp(NN / 16, BB, 2);
        proj_kernel<<<gp, 256, 0, stream>>>(key, query, Wk, Wq, bk, bq, ek, eq);
        vpack_kernel<<<288, 256, 0, stream>>>(value, Vp);
        dim3 ga(NN / 64, NN / 32, BB);
        attn_kernel<<<ga, 256, 0, stream>>>(ek, eq, wf, bf, Bp);
        dim3 gm(NN / 64, 16, BB);
        av_kernel<<<gm, 256, 0, stream>>>(Vp, Bp, out);
    }
}